// Round 2
// baseline (163.588 us; speedup 1.0000x reference)
//
#include <hip/hip_runtime.h>

// norm_conv: im2col(3x3 reflect) -> row-normalize -> GEMM[576x64], fused.
// Design: out = (patches@W - mean*colsum(W)) * inv_std.
//  - kernel 1: pre-pack W (fp32->bf16) into per-lane MFMA fragment layout in ws.
//  - kernel 2: 256 blocks (ONE IMAGE each -> exactly 1 block/CU), 512 thr (8 waves).
//    Image processed as 4 quarters (8 out rows each; 10 staged rows incl. halo),
//    software-pipelined: while quarter q computes (MFMA from LDS buf[cur]),
//    quarter q+1's global loads are issued in 16-channel chunks before each
//    MFMA tile and consumed (f2bf + ds_write into buf[cur^1]) after it.
//    Different buffer + different stats regions => no barrier needed between
//    compute-reads and stage-writes; only 2 barriers per quarter.
//  - Row reflection baked into staging (srow j holds input row reflect(qbase+j)),
//    so the main loop needs no row reflect. Col reflect precomputed per lane.
//  - MFMA operands swapped: mfma(Wfrag, patchfrag) -> D^T[row=channel][col=pixel];
//    stores are pixel-contiguous full 64B lines; mean/inv lane-uniform per tile.

#define STRIDE 68            // ushorts per pixel in LDS (136 B -> 34 banks, 2-way only)
#define QPIX   320           // 10 rows x 32 cols staged per quarter
#define QOUT   256           // 8 rows x 32 cols output per quarter

typedef __attribute__((ext_vector_type(8))) short bf16x8;
typedef __attribute__((ext_vector_type(4))) short bf16x4;
typedef __attribute__((ext_vector_type(4))) float f32x4;

__device__ __forceinline__ unsigned short f2bf(float f) {
    union { float f; unsigned u; } v; v.f = f;
    unsigned r = v.u + 0x7FFFu + ((v.u >> 16) & 1u);   // RNE
    return (unsigned short)(r >> 16);
}
__device__ __forceinline__ unsigned pack2(float a, float b) {
    return (unsigned)f2bf(a) | ((unsigned)f2bf(b) << 16);
}
__device__ __forceinline__ int reflect32(int x) {      // jnp.pad 'reflect', pad=1
    x = (x < 0) ? -x : x;
    return (x > 31) ? (62 - x) : x;
}

// ws layout: uint4 wf[4][18][64]  (ntg, ks, lane) -> 8 bf16 frag elements.
// W[k'][o]: o = ntg*16 + (lane&15), k' = ks*32 + (lane>>4)*8 + j,
// with reordered k' = (kh*3+kw)*64 + c  <->  reference k = c*9 + (kh*3+kw).
__global__ void reorder_w_kernel(const float* __restrict__ W, uint4* __restrict__ wf) {
    int idx = blockIdx.x * 256 + threadIdx.x;   // 0..4607
    if (idx >= 4608) return;
    int lane = idx & 63;
    int ks   = (idx >> 6) % 18;
    int ntg  = idx / 1152;
    int quad = lane >> 4;
    int o    = ntg * 16 + (lane & 15);
    unsigned short v[8];
    #pragma unroll
    for (int j = 0; j < 8; ++j) {
        int kp = ks * 32 + quad * 8 + j;
        int c  = kp & 63;
        int s  = kp >> 6;
        v[j] = f2bf(W[(c * 9 + s) * 64 + o]);
    }
    uint4 r;
    r.x = (unsigned)v[0] | ((unsigned)v[1] << 16);
    r.y = (unsigned)v[2] | ((unsigned)v[3] << 16);
    r.z = (unsigned)v[4] | ((unsigned)v[5] << 16);
    r.w = (unsigned)v[6] | ((unsigned)v[7] << 16);
    wf[idx] = r;
}

__global__ __launch_bounds__(512, 2)
void norm_conv_kernel(const float* __restrict__ a,
                      const uint4* __restrict__ wf,
                      float* __restrict__ out) {
    __shared__ unsigned short img[2][QPIX * STRIDE];   // 2 x 43,520 B
    __shared__ float csum[QPIX];                       // per staged pixel channel-sum
    __shared__ float cssq[QPIX];                       // per staged pixel channel-sumsq
    __shared__ float pairs[2 * QOUT];                  // (mean, inv) per out pixel of current quarter
    __shared__ float wcs[64];                          // colsum(W_bf16) per out channel

    const int tid  = threadIdx.x;
    const int b    = blockIdx.x;
    const int lane = tid & 63;
    const int wid  = tid >> 6;              // 8 waves
    const int ng   = wid & 1;               // n-half: o in [ng*32, ng*32+32)
    const int wq   = wid >> 1;              // m-quarter: 4 m-tiles each
    const int quad = lane >> 4;
    const int mlan = lane & 15;

    // ---- W fragments: 2 n-tiles x 18 k-steps, held in registers (AGPR-able) ----
    bf16x8 bfrag[2][18];
    #pragma unroll
    for (int nt = 0; nt < 2; ++nt) {
        #pragma unroll
        for (int ks = 0; ks < 18; ++ks) {
            union { uint4 u; bf16x8 v; } cvt;
            cvt.u = wf[((ng * 2 + nt) * 18 + ks) * 64 + lane];
            bfrag[nt][ks] = cvt.v;
        }
    }

    const float* Ab = a + (size_t)b * 65536;
    const int sp   = tid;                   // staging pixel (threads 0..319)
    const int scol = sp & 31;
    const int srow = sp >> 5;               // 0..9 when sp < QPIX

    // ---- prologue: stage quarter 0 into img[0] ----
    if (sp < QPIX) {
        const float* src = Ab + reflect32(srow - 1) * 32 + scol;  // row reflect baked in
        unsigned short* dst = &img[0][sp * STRIDE];
        float s = 0.f, q = 0.f;
        #pragma unroll 8
        for (int c = 0; c < 64; c += 2) {
            float v0 = src[c * 1024];                 // coalesced: lanes -> consecutive pixels
            float v1 = src[(c + 1) * 1024];
            s += v0 + v1;
            q += v0 * v0 + v1 * v1;
            *(unsigned*)&dst[c] = pack2(v0, v1);      // ds_write_b32, 2-way banked
        }
        csum[sp] = s;
        cssq[sp] = q;
    }

    // ---- colsum(W_bf16) per lane's two o-columns (exact vs the bf16 GEMM) ----
    float So[2];
    #pragma unroll
    for (int nt = 0; nt < 2; ++nt) {
        float s = 0.f;
        #pragma unroll
        for (int ks = 0; ks < 18; ++ks) {
            #pragma unroll
            for (int j = 0; j < 8; ++j) {
                union { unsigned u; float f; } cv;
                cv.u = ((unsigned)(unsigned short)bfrag[nt][ks][j]) << 16;
                s += cv.f;
            }
        }
        s += __shfl_xor(s, 16, 64);               // sum quads: each quad holds k' subset
        s += __shfl_xor(s, 32, 64);
        So[nt] = s;
    }
    if (wid < 2 && quad == 0) {                   // waves 0,1 cover ng=0,1
        wcs[ng * 32 + mlan]      = So[0];
        wcs[ng * 32 + 16 + mlan] = So[1];
    }
    __syncthreads();

    // ---- stats for quarter 0 (threads 256..511; box over channel sums) ----
    if (tid >= 256) {
        int lp = tid - 256;
        int hg = lp >> 5, wg = lp & 31;
        float s = 0.f, q = 0.f;
        #pragma unroll
        for (int kh = 0; kh < 3; ++kh) {
            int rb = (hg + kh) * 32;              // row reflect already baked into staging
            #pragma unroll
            for (int kw = 0; kw < 3; ++kw) {
                int p = rb + reflect32(wg + kw - 1);
                s += csum[p];
                q += cssq[p];
            }
        }
        float mean = s * (1.0f / 576.0f);
        float var  = (q - s * mean) * (1.0f / 575.0f);   // ddof=1
        pairs[lp * 2]     = mean;
        pairs[lp * 2 + 1] = rsqrtf(var);
    }
    __syncthreads();

    // preload this lane's 8 channel colsums (D^T rows = quad*4+r)
    float so0[4], so1[4];
    #pragma unroll
    for (int r = 0; r < 4; ++r) {
        so0[r] = wcs[ng * 32 + quad * 4 + r];
        so1[r] = wcs[ng * 32 + 16 + quad * 4 + r];
    }

    // col-reflect precompute (scalars, not arrays -> no scratch)
    const int wA0 = reflect32(mlan - 1);          // tile col-half 0: wl = mlan
    const int wA1 = mlan;
    const int wA2 = mlan + 1;                     // <= 16, in range
    const int wB0 = 15 + mlan;                    // tile col-half 1: wl = 16+mlan
    const int wB1 = 16 + mlan;
    const int wB2 = reflect32(17 + mlan);

    // ---- pipelined main loop over 4 quarters ----
    int cur = 0;
    for (int qi = 0; qi < 4; ++qi) {
        const bool do_stage = (qi < 3) && (sp < QPIX);
        const float* nsrc = do_stage
            ? (Ab + reflect32(qi * 8 + 7 + srow) * 32 + scol)   // (qi+1)*8 - 1 + srow
            : Ab;
        unsigned short* ndst = &img[cur ^ 1][(do_stage ? sp : 0) * STRIDE];
        float ns = 0.f, nq = 0.f;

        const char* imgc = (const char*)img[cur];
        float* outB = out + (size_t)b * 65536 + qi * 256;

        #pragma unroll
        for (int j = 0; j < 4; ++j) {
            // (a) issue next-quarter staging loads, chunk j = channels 16j..16j+15
            float vbuf[16];
            if (do_stage) {
                #pragma unroll
                for (int cc = 0; cc < 16; ++cc)
                    vbuf[cc] = nsrc[(j * 16 + cc) * 1024];
            }
            // (b) compute m-tile mt = wq*4 + j (latency of (a) hides under this)
            const int mt   = wq * 4 + j;
            const int row0 = wq * 2 + (j >> 1);   // quarter-local top row of box
            const int w0 = (j & 1) ? wB0 : wA0;
            const int w1 = (j & 1) ? wB1 : wA1;
            const int w2 = (j & 1) ? wB2 : wA2;
            int base9[9];
            #pragma unroll
            for (int kh = 0; kh < 3; ++kh) {
                int rb = (row0 + kh) * 32;
                base9[kh * 3 + 0] = ((rb + w0) * STRIDE + quad * 8) * 2;
                base9[kh * 3 + 1] = ((rb + w1) * STRIDE + quad * 8) * 2;
                base9[kh * 3 + 2] = ((rb + w2) * STRIDE + quad * 8) * 2;
            }
            f32x4 acc0 = {0.f, 0.f, 0.f, 0.f};
            f32x4 acc1 = {0.f, 0.f, 0.f, 0.f};
            #pragma unroll
            for (int ks = 0; ks < 18; ++ks) {
                int off = base9[ks >> 1] + (ks & 1) * 64;       // +32 channels on odd ks
                bf16x4 flo = *(const bf16x4*)(imgc + off);      // ds_read_b64 x2 (8B aligned)
                bf16x4 fhi = *(const bf16x4*)(imgc + off + 8);
                bf16x8 af  = __builtin_shufflevector(flo, fhi, 0, 1, 2, 3, 4, 5, 6, 7);
                acc0 = __builtin_amdgcn_mfma_f32_16x16x32_bf16(bfrag[0][ks], af, acc0, 0, 0, 0);
                acc1 = __builtin_amdgcn_mfma_f32_16x16x32_bf16(bfrag[1][ks], af, acc1, 0, 0, 0);
            }
            // epilogue: D^T -> 16 lanes store 16 consecutive pixels of one channel
            const int lp = mt * 16 + mlan;
            float2 mi = *(const float2*)&pairs[lp * 2];         // (mean, inv)
            float* op = outB + lp;
            #pragma unroll
            for (int r = 0; r < 4; ++r) {
                int oA = ng * 32 + quad * 4 + r;
                op[oA * 1024]        = (acc0[r] - mi.x * so0[r]) * mi.y;
                op[(oA + 16) * 1024] = (acc1[r] - mi.x * so1[r]) * mi.y;
            }
            // (c) consume chunk j: f2bf + ds_write into the OTHER buffer (no barrier
            //     needed: different img buffer; csum rewrite is pre-stats-barrier)
            if (do_stage) {
                #pragma unroll
                for (int cc = 0; cc < 16; cc += 2) {
                    float v0 = vbuf[cc], v1 = vbuf[cc + 1];
                    ns += v0 + v1;
                    nq += v0 * v0 + v1 * v1;
                    *(unsigned*)&ndst[j * 16 + cc] = pack2(v0, v1);
                }
            }
        }

        if (qi < 3) {
            if (do_stage) { csum[sp] = ns; cssq[sp] = nq; }
            __syncthreads();                       // staged data + csum ready
            if (tid >= 256) {                      // stats for quarter qi+1
                int lp = tid - 256;
                int hg = lp >> 5, wg = lp & 31;
                float s = 0.f, q = 0.f;
                #pragma unroll
                for (int kh = 0; kh < 3; ++kh) {
                    int rb = (hg + kh) * 32;
                    #pragma unroll
                    for (int kw = 0; kw < 3; ++kw) {
                        int p = rb + reflect32(wg + kw - 1);
                        s += csum[p];
                        q += cssq[p];
                    }
                }
                float mean = s * (1.0f / 576.0f);
                float var  = (q - s * mean) * (1.0f / 575.0f);
                pairs[lp * 2]     = mean;
                pairs[lp * 2 + 1] = rsqrtf(var);
            }
            __syncthreads();                       // pairs ready for next quarter
        }
        cur ^= 1;
    }
}

extern "C" void kernel_launch(void* const* d_in, const int* in_sizes, int n_in,
                              void* d_out, int out_size, void* d_ws, size_t ws_size,
                              hipStream_t stream) {
    const float* a = (const float*)d_in[0];
    const float* w = (const float*)d_in[1];
    float* out = (float*)d_out;
    uint4* wf = (uint4*)d_ws;                      // needs 4608*16 = 73,728 B
    reorder_w_kernel<<<dim3(18), dim3(256), 0, stream>>>(w, wf);
    norm_conv_kernel<<<dim3(256), dim3(512), 0, stream>>>(a, (const uint4*)wf, out);
}